// Round 3
// baseline (190.155 us; speedup 1.0000x reference)
//
#include <hip/hip_runtime.h>

// Capped simplex projection: per row, w = clip(z - tau, 0, u), sum(w) = 1.
// One wave (64 lanes) per row; 64 fp32 elements per lane in registers.
//
// R2 changes vs R1:
//  - fmed3 intrinsic for clip (guaranteed 1 instr; the min/max->med3 combine
//    is not guaranteed without fast-math).
//  - Two-phase bisection: 12 full-scan iters, then classify elements against
//    the interval (width < u): zero / capped / free contribute closed-form
//    C - A*tau; only elements inside the two narrow ambiguity bands (expected
//    ~1-3 per row) are rescanned in the remaining 12 iters, held in <=2 named
//    registers per lane. If any lane has >2 ambiguous, wave falls back to
//    full-scan iterations (safe for any data).

#define N_ASSETS 4096
#define N_SAMPLES 16384
#define MAX_W 0.02f
#define EPS 1e-7f
#define P1_ITERS 12
#define P2_ITERS 12

__device__ __forceinline__ float clipu(float v) {
    // median(v, 0, MAX_W) == clamp(v, 0, MAX_W); inputs are finite.
    return __builtin_amdgcn_fmed3f(v, 0.0f, MAX_W);
}

__device__ __forceinline__ float wave_sum(float s) {
    #pragma unroll
    for (int m = 1; m <= 32; m <<= 1) s += __shfl_xor(s, m);
    return s;
}

__global__ __launch_bounds__(256) void sparsemax_alloc_kernel(
    const float* __restrict__ x,
    const float* __restrict__ temperature,
    float* __restrict__ out) {

    const int wave = threadIdx.x >> 6;          // 4 waves per block
    const int lane = threadIdx.x & 63;
    const int row  = blockIdx.x * 4 + wave;
    if (row >= N_SAMPLES) return;

    const float4* xr   = reinterpret_cast<const float4*>(x + (size_t)row * N_ASSETS);
    float4*       outr = reinterpret_cast<float4*>(out + (size_t)row * N_ASSETS);

    const float rt = 1.0f / temperature[row];

    // Load 64 elements/lane as 16 coalesced float4s; z = x / temp.
    float4 z[16];
    #pragma unroll
    for (int k = 0; k < 16; ++k) {
        float4 v = xr[k * 64 + lane];
        z[k].x = v.x * rt; z[k].y = v.y * rt; z[k].z = v.z * rt; z[k].w = v.w * rt;
    }

    // Row min/max via per-lane then 64-lane butterfly.
    float mn = z[0].x, mx = z[0].x;
    #pragma unroll
    for (int k = 0; k < 16; ++k) {
        mn = fminf(mn, fminf(fminf(z[k].x, z[k].y), fminf(z[k].z, z[k].w)));
        mx = fmaxf(mx, fmaxf(fmaxf(z[k].x, z[k].y), fmaxf(z[k].z, z[k].w)));
    }
    #pragma unroll
    for (int m = 1; m <= 32; m <<= 1) {
        mn = fminf(mn, __shfl_xor(mn, m));
        mx = fmaxf(mx, __shfl_xor(mx, m));
    }

    float lo = mn - 1.0f;
    float hi = mx;

    // ---- Phase 1: full-scan bisection until interval width << u ----
    for (int it = 0; it < P1_ITERS; ++it) {
        const float mid = 0.5f * (lo + hi);
        float s0 = 0.0f, s1 = 0.0f, s2 = 0.0f, s3 = 0.0f;
        #pragma unroll
        for (int k = 0; k < 16; k += 4) {
            s0 += clipu(z[k+0].x - mid); s0 += clipu(z[k+0].y - mid);
            s0 += clipu(z[k+0].z - mid); s0 += clipu(z[k+0].w - mid);
            s1 += clipu(z[k+1].x - mid); s1 += clipu(z[k+1].y - mid);
            s1 += clipu(z[k+1].z - mid); s1 += clipu(z[k+1].w - mid);
            s2 += clipu(z[k+2].x - mid); s2 += clipu(z[k+2].y - mid);
            s2 += clipu(z[k+2].z - mid); s2 += clipu(z[k+2].w - mid);
            s3 += clipu(z[k+3].x - mid); s3 += clipu(z[k+3].y - mid);
            s3 += clipu(z[k+3].z - mid); s3 += clipu(z[k+3].w - mid);
        }
        float s = wave_sum((s0 + s1) + (s2 + s3));
        const bool too_big = s > 1.0f;
        lo = too_big ? mid : lo;
        hi = too_big ? hi : mid;
    }

    // ---- Split: classify vs [lo, hi]; all future taus lie in (lo, hi) ----
    // zero:  z <= lo          -> contributes 0 always
    // cap:   z >= hi + u      -> contributes u always
    // free:  hi < z < lo + u  -> contributes z - tau always
    // else ambiguous: keep up to 2 per lane in named registers.
    const float hi_pu = hi + MAX_W;
    const float lo_pu = lo + MAX_W;
    float C0 = 0.0f, C1 = 0.0f, A0 = 0.0f, A1 = 0.0f;
    float za = lo, zb = lo;   // absent slots: z - mid < 0 -> contribute 0
    int cnt = 0;
    #pragma unroll
    for (int k = 0; k < 16; ++k) {
        float zz[4] = {z[k].x, z[k].y, z[k].z, z[k].w};
        #pragma unroll
        for (int c = 0; c < 4; ++c) {
            const float v = zz[c];
            const bool isZero = v <= lo;
            const bool isCap  = v >= hi_pu;
            const bool isFree = (v > hi) && (v < lo_pu);
            const bool isAmb  = !(isZero || isCap || isFree);
            if (c & 1) {
                C1 += isCap ? MAX_W : (isFree ? v : 0.0f);
                A1 += isFree ? 1.0f : 0.0f;
            } else {
                C0 += isCap ? MAX_W : (isFree ? v : 0.0f);
                A0 += isFree ? 1.0f : 0.0f;
            }
            za = (isAmb && cnt == 0) ? v : za;
            zb = (isAmb && cnt == 1) ? v : zb;
            cnt += isAmb ? 1 : 0;
        }
    }
    const float Ct = wave_sum(C0 + C1);
    const float At = wave_sum(A0 + A1);
    const bool fast_ok = __all(cnt <= 2);

    // ---- Phase 2 ----
    if (fast_ok) {
        for (int it = 0; it < P2_ITERS; ++it) {
            const float mid = 0.5f * (lo + hi);
            float samb = clipu(za - mid) + clipu(zb - mid);
            samb = wave_sum(samb);
            const float s = fmaf(-At, mid, Ct) + samb;
            const bool too_big = s > 1.0f;
            lo = too_big ? mid : lo;
            hi = too_big ? hi : mid;
        }
    } else {
        for (int it = 0; it < P2_ITERS; ++it) {
            const float mid = 0.5f * (lo + hi);
            float s0 = 0.0f, s1 = 0.0f, s2 = 0.0f, s3 = 0.0f;
            #pragma unroll
            for (int k = 0; k < 16; k += 4) {
                s0 += clipu(z[k+0].x - mid); s0 += clipu(z[k+0].y - mid);
                s0 += clipu(z[k+0].z - mid); s0 += clipu(z[k+0].w - mid);
                s1 += clipu(z[k+1].x - mid); s1 += clipu(z[k+1].y - mid);
                s1 += clipu(z[k+1].z - mid); s1 += clipu(z[k+1].w - mid);
                s2 += clipu(z[k+2].x - mid); s2 += clipu(z[k+2].y - mid);
                s2 += clipu(z[k+2].z - mid); s2 += clipu(z[k+2].w - mid);
                s3 += clipu(z[k+3].x - mid); s3 += clipu(z[k+3].y - mid);
                s3 += clipu(z[k+3].z - mid); s3 += clipu(z[k+3].w - mid);
            }
            float s = wave_sum((s0 + s1) + (s2 + s3));
            const bool too_big = s > 1.0f;
            lo = too_big ? mid : lo;
            hi = too_big ? hi : mid;
        }
    }
    const float tau0 = 0.5f * (lo + hi);

    // ---- Active set at tau0 (same semantics as reference) ----
    const float ucut = MAX_W - EPS;
    float sf0 = 0.0f, sf1 = 0.0f, nf0 = 0.0f, nf1 = 0.0f, nc0 = 0.0f, nc1 = 0.0f;
    #pragma unroll
    for (int k = 0; k < 16; k += 2) {
        float zza[4] = {z[k].x, z[k].y, z[k].z, z[k].w};
        float zzb[4] = {z[k+1].x, z[k+1].y, z[k+1].z, z[k+1].w};
        #pragma unroll
        for (int c = 0; c < 4; ++c) {
            const float wa = clipu(zza[c] - tau0);
            const bool fra = (wa > EPS) && (wa < ucut);
            const bool cpa = (wa >= ucut);
            sf0 += fra ? zza[c] : 0.0f;
            nf0 += fra ? 1.0f : 0.0f;
            nc0 += cpa ? 1.0f : 0.0f;
            const float wb = clipu(zzb[c] - tau0);
            const bool frb = (wb > EPS) && (wb < ucut);
            const bool cpb = (wb >= ucut);
            sf1 += frb ? zzb[c] : 0.0f;
            nf1 += frb ? 1.0f : 0.0f;
            nc1 += cpb ? 1.0f : 0.0f;
        }
    }
    const float s_free = wave_sum(sf0 + sf1);
    const float n_free = wave_sum(nf0 + nf1);
    const float n_cap  = wave_sum(nc0 + nc1);
    const float tau = (s_free + MAX_W * n_cap - 1.0f) / fmaxf(n_free, 1.0f);

    // ---- Final write: free ? z - tau : (capped ? u : 0) ----
    #pragma unroll
    for (int k = 0; k < 16; ++k) {
        float zz[4] = {z[k].x, z[k].y, z[k].z, z[k].w};
        float4 o;
        float* oo = &o.x;
        #pragma unroll
        for (int c = 0; c < 4; ++c) {
            const float w0 = clipu(zz[c] - tau0);
            const bool fr = (w0 > EPS) && (w0 < ucut);
            const bool cp = (w0 >= ucut);
            oo[c] = fr ? (zz[c] - tau) : (cp ? MAX_W : 0.0f);
        }
        outr[k * 64 + lane] = o;
    }
}

extern "C" void kernel_launch(void* const* d_in, const int* in_sizes, int n_in,
                              void* d_out, int out_size, void* d_ws, size_t ws_size,
                              hipStream_t stream) {
    const float* x    = (const float*)d_in[0];
    const float* temp = (const float*)d_in[1];
    float* out = (float*)d_out;
    (void)in_sizes; (void)n_in; (void)out_size; (void)d_ws; (void)ws_size;

    dim3 grid(N_SAMPLES / 4);   // 4 rows (waves) per 256-thread block
    dim3 block(256);
    hipLaunchKernelGGL(sparsemax_alloc_kernel, grid, block, 0, stream, x, temp, out);
}

// Round 5
// 151.817 us; speedup vs baseline: 1.2525x; 1.2525x over previous
//
#include <hip/hip_runtime.h>

// Capped simplex projection: per row, w = clip(z - tau, 0, u), sum(w) = 1.
// One wave (64 lanes) per row; 64 fp32 elements per lane in registers.
//
// R4 = R3 with DPP ctrl codes as template parameters (the builtin requires
// integer-constant arguments at the call site).
//  - All wave reductions via DPP (VALU latency) instead of __shfl_xor.
//  - Phase 2: ambiguous z's broadcast via wave-private LDS compaction, then
//    64-way multisection: each lane evaluates closed-form s(tau) at its own
//    tau; one ballot per round, 6 bits/round, 3 rounds.
//  - Fallback to full-scan bisection if >8 ambiguous (correct for any data).

#define N_ASSETS 4096
#define N_SAMPLES 16384
#define MAX_W 0.02f
#define EPS 1e-7f
#define P1_ITERS 12
#define FB_ITERS 24          // fallback full-scan iterations
#define MS_ROUNDS 3          // multisection rounds (6 bits each)

__device__ __forceinline__ float clipu(float v) {
    return __builtin_amdgcn_fmed3f(v, 0.0f, MAX_W);
}

__device__ __forceinline__ float bc_int_as_f(int v) {
    union { int i; float f; } u; u.i = v; return u.f;
}
__device__ __forceinline__ int bc_f_as_int(float v) {
    union { int i; float f; } u; u.f = v; return u.i;
}

// DPP-based wave64 reductions. ctrl/masks must be compile-time constants.
template <int CTRL, int RMASK, bool BC>
__device__ __forceinline__ float dpp_add_step(float x) {
    int t = __builtin_amdgcn_update_dpp(0, bc_f_as_int(x), CTRL, RMASK, 0xF, BC);
    return x + bc_int_as_f(t);
}
__device__ __forceinline__ float wave_sum(float v) {
    v = dpp_add_step<0x111, 0xF, true>(v);   // row_shr:1
    v = dpp_add_step<0x112, 0xF, true>(v);   // row_shr:2
    v = dpp_add_step<0x114, 0xF, true>(v);   // row_shr:4
    v = dpp_add_step<0x118, 0xF, true>(v);   // row_shr:8
    v = dpp_add_step<0x142, 0xA, false>(v);  // row_bcast:15 -> rows 1,3
    v = dpp_add_step<0x143, 0xC, false>(v);  // row_bcast:31 -> row 2,3
    return bc_int_as_f(__builtin_amdgcn_readlane(bc_f_as_int(v), 63));
}
template <int CTRL, int RMASK>
__device__ __forceinline__ float dpp_min_step(float x) {
    int xi = bc_f_as_int(x);
    int t = __builtin_amdgcn_update_dpp(xi, xi, CTRL, RMASK, 0xF, false);
    return fminf(x, bc_int_as_f(t));
}
template <int CTRL, int RMASK>
__device__ __forceinline__ float dpp_max_step(float x) {
    int xi = bc_f_as_int(x);
    int t = __builtin_amdgcn_update_dpp(xi, xi, CTRL, RMASK, 0xF, false);
    return fmaxf(x, bc_int_as_f(t));
}
__device__ __forceinline__ float wave_min(float v) {
    v = dpp_min_step<0x111, 0xF>(v); v = dpp_min_step<0x112, 0xF>(v);
    v = dpp_min_step<0x114, 0xF>(v); v = dpp_min_step<0x118, 0xF>(v);
    v = dpp_min_step<0x142, 0xA>(v); v = dpp_min_step<0x143, 0xC>(v);
    return bc_int_as_f(__builtin_amdgcn_readlane(bc_f_as_int(v), 63));
}
__device__ __forceinline__ float wave_max(float v) {
    v = dpp_max_step<0x111, 0xF>(v); v = dpp_max_step<0x112, 0xF>(v);
    v = dpp_max_step<0x114, 0xF>(v); v = dpp_max_step<0x118, 0xF>(v);
    v = dpp_max_step<0x142, 0xA>(v); v = dpp_max_step<0x143, 0xC>(v);
    return bc_int_as_f(__builtin_amdgcn_readlane(bc_f_as_int(v), 63));
}

__global__ __launch_bounds__(256) void sparsemax_alloc_kernel(
    const float* __restrict__ x,
    const float* __restrict__ temperature,
    float* __restrict__ out) {

    __shared__ float amb_lds[4][16];

    const int wave = threadIdx.x >> 6;          // 4 waves per block
    const int lane = threadIdx.x & 63;
    const int row  = blockIdx.x * 4 + wave;
    if (row >= N_SAMPLES) return;

    const float4* xr   = reinterpret_cast<const float4*>(x + (size_t)row * N_ASSETS);
    float4*       outr = reinterpret_cast<float4*>(out + (size_t)row * N_ASSETS);

    const float rt = 1.0f / temperature[row];

    // Load 64 elements/lane as 16 coalesced float4s; z = x / temp.
    float4 z[16];
    #pragma unroll
    for (int k = 0; k < 16; ++k) {
        float4 v = xr[k * 64 + lane];
        z[k].x = v.x * rt; z[k].y = v.y * rt; z[k].z = v.z * rt; z[k].w = v.w * rt;
    }

    // Row min/max.
    float mn = z[0].x, mx = z[0].x;
    #pragma unroll
    for (int k = 0; k < 16; ++k) {
        mn = fminf(mn, fminf(fminf(z[k].x, z[k].y), fminf(z[k].z, z[k].w)));
        mx = fmaxf(mx, fmaxf(fmaxf(z[k].x, z[k].y), fmaxf(z[k].z, z[k].w)));
    }
    mn = wave_min(mn);
    mx = wave_max(mx);

    float lo = mn - 1.0f;
    float hi = mx;

    // ---- Phase 1: full-scan bisection until interval width << u ----
    for (int it = 0; it < P1_ITERS; ++it) {
        const float mid = 0.5f * (lo + hi);
        float s0 = 0.0f, s1 = 0.0f, s2 = 0.0f, s3 = 0.0f;
        #pragma unroll
        for (int k = 0; k < 16; k += 4) {
            s0 += clipu(z[k+0].x - mid); s0 += clipu(z[k+0].y - mid);
            s0 += clipu(z[k+0].z - mid); s0 += clipu(z[k+0].w - mid);
            s1 += clipu(z[k+1].x - mid); s1 += clipu(z[k+1].y - mid);
            s1 += clipu(z[k+1].z - mid); s1 += clipu(z[k+1].w - mid);
            s2 += clipu(z[k+2].x - mid); s2 += clipu(z[k+2].y - mid);
            s2 += clipu(z[k+2].z - mid); s2 += clipu(z[k+2].w - mid);
            s3 += clipu(z[k+3].x - mid); s3 += clipu(z[k+3].y - mid);
            s3 += clipu(z[k+3].z - mid); s3 += clipu(z[k+3].w - mid);
        }
        const float s = wave_sum((s0 + s1) + (s2 + s3));
        const bool too_big = s > 1.0f;
        lo = too_big ? mid : lo;
        hi = too_big ? hi : mid;
    }

    // ---- Split: classify vs [lo, hi]; all future taus lie in (lo, hi] ----
    const float hi_pu = hi + MAX_W;
    const float lo_pu = lo + MAX_W;
    float C0 = 0.0f, C1 = 0.0f, A0 = 0.0f, A1 = 0.0f;
    float za = lo, zb = lo;
    int cnt = 0;
    #pragma unroll
    for (int k = 0; k < 16; ++k) {
        float zz[4] = {z[k].x, z[k].y, z[k].z, z[k].w};
        #pragma unroll
        for (int c = 0; c < 4; ++c) {
            const float v = zz[c];
            const bool isZero = v <= lo;
            const bool isCap  = v >= hi_pu;
            const bool isFree = (v > hi) && (v < lo_pu);
            const bool isAmb  = !(isZero || isCap || isFree);
            if (c & 1) { C1 += isCap ? MAX_W : (isFree ? v : 0.0f); A1 += isFree ? 1.0f : 0.0f; }
            else       { C0 += isCap ? MAX_W : (isFree ? v : 0.0f); A0 += isFree ? 1.0f : 0.0f; }
            za = (isAmb && cnt == 0) ? v : za;
            zb = (isAmb && cnt == 1) ? v : zb;
            cnt += isAmb ? 1 : 0;
        }
    }
    const float Ct = wave_sum(C0 + C1);
    const float At = wave_sum(A0 + A1);

    // Compact ambiguous values into wave-private LDS, broadcast to all lanes.
    const unsigned long long b1 = __ballot(cnt >= 1);
    const unsigned long long b2 = __ballot(cnt >= 2);
    int off = __builtin_amdgcn_mbcnt_hi((unsigned)(b1 >> 32),
              __builtin_amdgcn_mbcnt_lo((unsigned)b1, 0));
    off    += __builtin_amdgcn_mbcnt_hi((unsigned)(b2 >> 32),
              __builtin_amdgcn_mbcnt_lo((unsigned)b2, 0));
    const int M = __popcll(b1) + __popcll(b2);

    if (cnt >= 1 && off < 16)     amb_lds[wave][off]     = za;
    if (cnt >= 2 && off + 1 < 16) amb_lds[wave][off + 1] = zb;
    asm volatile("s_waitcnt lgkmcnt(0)" ::: "memory");

    float a0 = (0 < M) ? amb_lds[wave][0] : lo;
    float a1 = (1 < M) ? amb_lds[wave][1] : lo;
    float a2 = (2 < M) ? amb_lds[wave][2] : lo;
    float a3 = (3 < M) ? amb_lds[wave][3] : lo;
    float a4 = (4 < M) ? amb_lds[wave][4] : lo;
    float a5 = (5 < M) ? amb_lds[wave][5] : lo;
    float a6 = (6 < M) ? amb_lds[wave][6] : lo;
    float a7 = (7 < M) ? amb_lds[wave][7] : lo;

    // ---- Phase 2 ----
    if (M <= 8) {
        // 64-way multisection on the closed form; no cross-lane reduce inside.
        #pragma unroll
        for (int r = 0; r < MS_ROUNDS; ++r) {
            const float step = (hi - lo) * (1.0f / 64.0f);
            const float tl = fmaf((float)(lane + 1), step, lo);
            float s = fmaf(-At, tl, Ct);
            s += clipu(a0 - tl); s += clipu(a1 - tl);
            s += clipu(a2 - tl); s += clipu(a3 - tl);
            s += clipu(a4 - tl); s += clipu(a5 - tl);
            s += clipu(a6 - tl); s += clipu(a7 - tl);
            const unsigned long long mask = __ballot(s > 1.0f);
            int j = __popcll(mask);
            j = (j > 63) ? 63 : j;
            const float lo_old = lo;
            lo = fmaf((float)j, step, lo_old);
            hi = fmaf((float)(j + 1), step, lo_old);
        }
    } else {
        for (int it = 0; it < FB_ITERS; ++it) {
            const float mid = 0.5f * (lo + hi);
            float s0 = 0.0f, s1 = 0.0f, s2 = 0.0f, s3 = 0.0f;
            #pragma unroll
            for (int k = 0; k < 16; k += 4) {
                s0 += clipu(z[k+0].x - mid); s0 += clipu(z[k+0].y - mid);
                s0 += clipu(z[k+0].z - mid); s0 += clipu(z[k+0].w - mid);
                s1 += clipu(z[k+1].x - mid); s1 += clipu(z[k+1].y - mid);
                s1 += clipu(z[k+1].z - mid); s1 += clipu(z[k+1].w - mid);
                s2 += clipu(z[k+2].x - mid); s2 += clipu(z[k+2].y - mid);
                s2 += clipu(z[k+2].z - mid); s2 += clipu(z[k+2].w - mid);
                s3 += clipu(z[k+3].x - mid); s3 += clipu(z[k+3].y - mid);
                s3 += clipu(z[k+3].z - mid); s3 += clipu(z[k+3].w - mid);
            }
            const float s = wave_sum((s0 + s1) + (s2 + s3));
            const bool too_big = s > 1.0f;
            lo = too_big ? mid : lo;
            hi = too_big ? hi : mid;
        }
    }
    const float tau0 = 0.5f * (lo + hi);

    // ---- Active set at tau0 (same semantics as reference) ----
    const float ucut = MAX_W - EPS;
    float sf0 = 0.0f, sf1 = 0.0f, nf0 = 0.0f, nf1 = 0.0f, nc0 = 0.0f, nc1 = 0.0f;
    #pragma unroll
    for (int k = 0; k < 16; k += 2) {
        float zza[4] = {z[k].x, z[k].y, z[k].z, z[k].w};
        float zzb[4] = {z[k+1].x, z[k+1].y, z[k+1].z, z[k+1].w};
        #pragma unroll
        for (int c = 0; c < 4; ++c) {
            const float wa = clipu(zza[c] - tau0);
            const bool fra = (wa > EPS) && (wa < ucut);
            const bool cpa = (wa >= ucut);
            sf0 += fra ? zza[c] : 0.0f;
            nf0 += fra ? 1.0f : 0.0f;
            nc0 += cpa ? 1.0f : 0.0f;
            const float wb = clipu(zzb[c] - tau0);
            const bool frb = (wb > EPS) && (wb < ucut);
            const bool cpb = (wb >= ucut);
            sf1 += frb ? zzb[c] : 0.0f;
            nf1 += frb ? 1.0f : 0.0f;
            nc1 += cpb ? 1.0f : 0.0f;
        }
    }
    const float s_free = wave_sum(sf0 + sf1);
    const float n_free = wave_sum(nf0 + nf1);
    const float n_cap  = wave_sum(nc0 + nc1);
    const float tau = (s_free + MAX_W * n_cap - 1.0f) / fmaxf(n_free, 1.0f);

    // ---- Final write: free ? z - tau : (capped ? u : 0) ----
    #pragma unroll
    for (int k = 0; k < 16; ++k) {
        float zz[4] = {z[k].x, z[k].y, z[k].z, z[k].w};
        float4 o;
        float* oo = &o.x;
        #pragma unroll
        for (int c = 0; c < 4; ++c) {
            const float w0 = clipu(zz[c] - tau0);
            const bool fr = (w0 > EPS) && (w0 < ucut);
            const bool cp = (w0 >= ucut);
            oo[c] = fr ? (zz[c] - tau) : (cp ? MAX_W : 0.0f);
        }
        outr[k * 64 + lane] = o;
    }
}

extern "C" void kernel_launch(void* const* d_in, const int* in_sizes, int n_in,
                              void* d_out, int out_size, void* d_ws, size_t ws_size,
                              hipStream_t stream) {
    const float* x    = (const float*)d_in[0];
    const float* temp = (const float*)d_in[1];
    float* out = (float*)d_out;
    (void)in_sizes; (void)n_in; (void)out_size; (void)d_ws; (void)ws_size;

    dim3 grid(N_SAMPLES / 4);   // 4 rows (waves) per 256-thread block
    dim3 block(256);
    hipLaunchKernelGGL(sparsemax_alloc_kernel, grid, block, 0, stream, x, temp, out);
}

// Round 6
// 127.719 us; speedup vs baseline: 1.4889x; 1.1887x over previous
//
#include <hip/hip_runtime.h>

// Capped simplex projection: per row, w = clip(z - tau, 0, u), sum(w) = 1.
// One wave (64 lanes) per row; 64 fp32 elements per lane in registers.
//
// R5 changes vs R4:
//  - v_pk_add_f32 / v_pk_mul_f32 (packed 2xfp32, CDNA VOP3P) via inline asm
//    for the scan sub/accumulate, z-scale, MS rounds, epilogue subs: the
//    dominant scan body drops from 6 to 4 insts per 2 elements.
//  - P1 12 -> 9 iters; ambiguity capacity 3/lane, 16 total (LDS), multisection
//    evaluates 16 taps (8 packed pairs). Fallback to 18 scalar full scans if
//    capacity exceeded (correct for any data; probability ~1e-3).
//  - Total bisection bits 9 + 3*6 = 27 (delta ~1e-7); output accuracy is
//    bf16-comparison-floor-limited (2^-13), so large slack remains.

#define N_ASSETS 4096
#define N_SAMPLES 16384
#define MAX_W 0.02f
#define EPS 1e-7f
#define P1_ITERS 9
#define FB_ITERS 18          // fallback full-scan iterations
#define MS_ROUNDS 3          // multisection rounds (6 bits each)

typedef __attribute__((ext_vector_type(2))) float f32x2;

#define PKADD(d, a, b) asm("v_pk_add_f32 %0, %1, %2" : "=v"(d) : "v"(a), "v"(b))
#define PKMUL(d, a, b) asm("v_pk_mul_f32 %0, %1, %2" : "=v"(d) : "v"(a), "v"(b))

__device__ __forceinline__ float clipu(float v) {
    return __builtin_amdgcn_fmed3f(v, 0.0f, MAX_W);
}

__device__ __forceinline__ float bc_int_as_f(int v) {
    union { int i; float f; } u; u.i = v; return u.f;
}
__device__ __forceinline__ int bc_f_as_int(float v) {
    union { int i; float f; } u; u.f = v; return u.i;
}

// DPP-based wave64 reductions (ctrl codes must be compile-time constants).
template <int CTRL, int RMASK, bool BC>
__device__ __forceinline__ float dpp_add_step(float x) {
    int t = __builtin_amdgcn_update_dpp(0, bc_f_as_int(x), CTRL, RMASK, 0xF, BC);
    return x + bc_int_as_f(t);
}
__device__ __forceinline__ float wave_sum(float v) {
    v = dpp_add_step<0x111, 0xF, true>(v);   // row_shr:1
    v = dpp_add_step<0x112, 0xF, true>(v);   // row_shr:2
    v = dpp_add_step<0x114, 0xF, true>(v);   // row_shr:4
    v = dpp_add_step<0x118, 0xF, true>(v);   // row_shr:8
    v = dpp_add_step<0x142, 0xA, false>(v);  // row_bcast:15
    v = dpp_add_step<0x143, 0xC, false>(v);  // row_bcast:31
    return bc_int_as_f(__builtin_amdgcn_readlane(bc_f_as_int(v), 63));
}
template <int CTRL, int RMASK>
__device__ __forceinline__ float dpp_min_step(float x) {
    int xi = bc_f_as_int(x);
    int t = __builtin_amdgcn_update_dpp(xi, xi, CTRL, RMASK, 0xF, false);
    return fminf(x, bc_int_as_f(t));
}
template <int CTRL, int RMASK>
__device__ __forceinline__ float dpp_max_step(float x) {
    int xi = bc_f_as_int(x);
    int t = __builtin_amdgcn_update_dpp(xi, xi, CTRL, RMASK, 0xF, false);
    return fmaxf(x, bc_int_as_f(t));
}
__device__ __forceinline__ float wave_min(float v) {
    v = dpp_min_step<0x111, 0xF>(v); v = dpp_min_step<0x112, 0xF>(v);
    v = dpp_min_step<0x114, 0xF>(v); v = dpp_min_step<0x118, 0xF>(v);
    v = dpp_min_step<0x142, 0xA>(v); v = dpp_min_step<0x143, 0xC>(v);
    return bc_int_as_f(__builtin_amdgcn_readlane(bc_f_as_int(v), 63));
}
__device__ __forceinline__ float wave_max(float v) {
    v = dpp_max_step<0x111, 0xF>(v); v = dpp_max_step<0x112, 0xF>(v);
    v = dpp_max_step<0x114, 0xF>(v); v = dpp_max_step<0x118, 0xF>(v);
    v = dpp_max_step<0x142, 0xA>(v); v = dpp_max_step<0x143, 0xC>(v);
    return bc_int_as_f(__builtin_amdgcn_readlane(bc_f_as_int(v), 63));
}

// Full packed scan: sum of clip(z - mid) over 32 pairs.
__device__ __forceinline__ float scan_sum(const f32x2* zp, float mid) {
    f32x2 nm; nm.x = -mid; nm.y = -mid;
    f32x2 acc0 = {0.f, 0.f}, acc1 = {0.f, 0.f}, acc2 = {0.f, 0.f}, acc3 = {0.f, 0.f};
    #pragma unroll
    for (int k = 0; k < 32; k += 4) {
        f32x2 t0, t1, t2, t3;
        PKADD(t0, zp[k+0], nm);
        PKADD(t1, zp[k+1], nm);
        PKADD(t2, zp[k+2], nm);
        PKADD(t3, zp[k+3], nm);
        t0.x = clipu(t0.x); t0.y = clipu(t0.y);
        t1.x = clipu(t1.x); t1.y = clipu(t1.y);
        t2.x = clipu(t2.x); t2.y = clipu(t2.y);
        t3.x = clipu(t3.x); t3.y = clipu(t3.y);
        PKADD(acc0, acc0, t0);
        PKADD(acc1, acc1, t1);
        PKADD(acc2, acc2, t2);
        PKADD(acc3, acc3, t3);
    }
    PKADD(acc0, acc0, acc1);
    PKADD(acc2, acc2, acc3);
    PKADD(acc0, acc0, acc2);
    return acc0.x + acc0.y;
}

__global__ __launch_bounds__(256) void sparsemax_alloc_kernel(
    const float* __restrict__ x,
    const float* __restrict__ temperature,
    float* __restrict__ out) {

    __shared__ float amb_lds[4][16];

    const int wave = threadIdx.x >> 6;          // 4 waves per block
    const int lane = threadIdx.x & 63;
    const int row  = blockIdx.x * 4 + wave;
    if (row >= N_SAMPLES) return;

    const float4* xr   = reinterpret_cast<const float4*>(x + (size_t)row * N_ASSETS);
    float4*       outr = reinterpret_cast<float4*>(out + (size_t)row * N_ASSETS);

    const float rt = 1.0f / temperature[row];
    f32x2 rt2; rt2.x = rt; rt2.y = rt;

    // Load 64 elements/lane as 16 coalesced float4s; z = x / temp (packed mul).
    f32x2 zp[32];
    #pragma unroll
    for (int k = 0; k < 16; ++k) {
        float4 v = xr[k * 64 + lane];
        f32x2 lohalf, hihalf;
        lohalf.x = v.x; lohalf.y = v.y;
        hihalf.x = v.z; hihalf.y = v.w;
        PKMUL(zp[2*k],   lohalf, rt2);
        PKMUL(zp[2*k+1], hihalf, rt2);
    }

    // Row min/max.
    float mn = zp[0].x, mx = zp[0].x;
    #pragma unroll
    for (int k = 0; k < 32; ++k) {
        mn = fminf(mn, fminf(zp[k].x, zp[k].y));
        mx = fmaxf(mx, fmaxf(zp[k].x, zp[k].y));
    }
    mn = wave_min(mn);
    mx = wave_max(mx);

    float lo = mn - 1.0f;
    float hi = mx;

    // ---- Phase 1: full-scan bisection (packed) ----
    for (int it = 0; it < P1_ITERS; ++it) {
        const float mid = 0.5f * (lo + hi);
        const float s = wave_sum(scan_sum(zp, mid));
        const bool too_big = s > 1.0f;
        lo = too_big ? mid : lo;
        hi = too_big ? hi : mid;
    }

    // ---- Split: classify vs [lo, hi]; all future taus lie in (lo, hi] ----
    const float hi_pu = hi + MAX_W;
    const float lo_pu = lo + MAX_W;
    float C0 = 0.0f, C1 = 0.0f, A0 = 0.0f, A1 = 0.0f;
    float za = lo, zb = lo, zc = lo;
    int cnt = 0;
    #pragma unroll
    for (int k = 0; k < 32; ++k) {
        #pragma unroll
        for (int c = 0; c < 2; ++c) {
            const float v = (c == 0) ? zp[k].x : zp[k].y;
            const bool isZero = v <= lo;
            const bool isCap  = v >= hi_pu;
            const bool isFree = (v > hi) && (v < lo_pu);
            const bool isAmb  = !(isZero || isCap || isFree);
            if (c) { C1 += isCap ? MAX_W : (isFree ? v : 0.0f); A1 += isFree ? 1.0f : 0.0f; }
            else   { C0 += isCap ? MAX_W : (isFree ? v : 0.0f); A0 += isFree ? 1.0f : 0.0f; }
            za = (isAmb && cnt == 0) ? v : za;
            zb = (isAmb && cnt == 1) ? v : zb;
            zc = (isAmb && cnt == 2) ? v : zc;
            cnt += isAmb ? 1 : 0;
        }
    }
    const float Ct = wave_sum(C0 + C1);
    const float At = wave_sum(A0 + A1);

    // Compact ambiguous values into wave-private LDS (16 slots).
    const unsigned long long b1 = __ballot(cnt >= 1);
    const unsigned long long b2 = __ballot(cnt >= 2);
    const unsigned long long b3 = __ballot(cnt >= 3);
    const unsigned long long b4 = __ballot(cnt >= 4);
    int off = __builtin_amdgcn_mbcnt_hi((unsigned)(b1 >> 32),
              __builtin_amdgcn_mbcnt_lo((unsigned)b1, 0));
    off    += __builtin_amdgcn_mbcnt_hi((unsigned)(b2 >> 32),
              __builtin_amdgcn_mbcnt_lo((unsigned)b2, 0));
    off    += __builtin_amdgcn_mbcnt_hi((unsigned)(b3 >> 32),
              __builtin_amdgcn_mbcnt_lo((unsigned)b3, 0));
    const int M = __popcll(b1) + __popcll(b2) + __popcll(b3);

    if (cnt >= 1 && off     < 16) amb_lds[wave][off]     = za;
    if (cnt >= 2 && off + 1 < 16) amb_lds[wave][off + 1] = zb;
    if (cnt >= 3 && off + 2 < 16) amb_lds[wave][off + 2] = zc;
    asm volatile("s_waitcnt lgkmcnt(0)" ::: "memory");

    const bool fast_ok = (b4 == 0ULL) && (M <= 16);

    // ---- Phase 2 ----
    if (fast_ok) {
        // Hoist up to 16 taps (8 packed pairs); absent slots -> lo (contributes 0).
        f32x2 a2[8];
        #pragma unroll
        for (int i = 0; i < 8; ++i) {
            const float u0 = (2*i     < M) ? amb_lds[wave][2*i]     : lo;
            const float u1 = (2*i + 1 < M) ? amb_lds[wave][2*i + 1] : lo;
            a2[i].x = u0; a2[i].y = u1;
        }
        // 64-way multisection on the closed form; one ballot per round.
        #pragma unroll
        for (int r = 0; r < MS_ROUNDS; ++r) {
            const float step = (hi - lo) * 0.015625f;
            const float tl = fmaf((float)(lane + 1), step, lo);
            f32x2 ntl; ntl.x = -tl; ntl.y = -tl;
            f32x2 acc0 = {0.f, 0.f}, acc1 = {0.f, 0.f};
            #pragma unroll
            for (int i = 0; i < 8; i += 2) {
                f32x2 t0, t1;
                PKADD(t0, a2[i],   ntl);
                PKADD(t1, a2[i+1], ntl);
                t0.x = clipu(t0.x); t0.y = clipu(t0.y);
                t1.x = clipu(t1.x); t1.y = clipu(t1.y);
                PKADD(acc0, acc0, t0);
                PKADD(acc1, acc1, t1);
            }
            PKADD(acc0, acc0, acc1);
            const float s = fmaf(-At, tl, Ct) + (acc0.x + acc0.y);
            const unsigned long long mask = __ballot(s > 1.0f);
            int j = __popcll(mask);
            j = (j > 63) ? 63 : j;
            const float lo_old = lo;
            lo = fmaf((float)j, step, lo_old);
            hi = fmaf((float)(j + 1), step, lo_old);
        }
    } else {
        for (int it = 0; it < FB_ITERS; ++it) {
            const float mid = 0.5f * (lo + hi);
            const float s = wave_sum(scan_sum(zp, mid));
            const bool too_big = s > 1.0f;
            lo = too_big ? mid : lo;
            hi = too_big ? hi : mid;
        }
    }
    const float tau0 = 0.5f * (lo + hi);

    // ---- Active set at tau0 (same semantics as reference) ----
    const float ucut = MAX_W - EPS;
    f32x2 nt0; nt0.x = -tau0; nt0.y = -tau0;
    float sf0 = 0.0f, sf1 = 0.0f, nf0 = 0.0f, nf1 = 0.0f, nc0 = 0.0f, nc1 = 0.0f;
    #pragma unroll
    for (int k = 0; k < 32; k += 2) {
        f32x2 t0, t1;
        PKADD(t0, zp[k],   nt0);
        PKADD(t1, zp[k+1], nt0);
        const float w0a = clipu(t0.x), w0b = clipu(t0.y);
        const float w0c = clipu(t1.x), w0d = clipu(t1.y);
        const bool fra = (w0a > EPS) && (w0a < ucut);
        const bool frb = (w0b > EPS) && (w0b < ucut);
        const bool frc = (w0c > EPS) && (w0c < ucut);
        const bool frd = (w0d > EPS) && (w0d < ucut);
        sf0 += fra ? zp[k].x   : 0.0f;  nf0 += fra ? 1.0f : 0.0f;
        sf1 += frb ? zp[k].y   : 0.0f;  nf1 += frb ? 1.0f : 0.0f;
        sf0 += frc ? zp[k+1].x : 0.0f;  nf0 += frc ? 1.0f : 0.0f;
        sf1 += frd ? zp[k+1].y : 0.0f;  nf1 += frd ? 1.0f : 0.0f;
        nc0 += (w0a >= ucut) ? 1.0f : 0.0f;
        nc1 += (w0b >= ucut) ? 1.0f : 0.0f;
        nc0 += (w0c >= ucut) ? 1.0f : 0.0f;
        nc1 += (w0d >= ucut) ? 1.0f : 0.0f;
    }
    const float s_free = wave_sum(sf0 + sf1);
    const float n_free = wave_sum(nf0 + nf1);
    const float n_cap  = wave_sum(nc0 + nc1);
    const float tau = (s_free + MAX_W * n_cap - 1.0f) / fmaxf(n_free, 1.0f);

    // ---- Final write: free ? z - tau : (capped ? u : 0) ----
    f32x2 ntau; ntau.x = -tau; ntau.y = -tau;
    #pragma unroll
    for (int k = 0; k < 16; ++k) {
        f32x2 t0, t1, w0, w1;
        PKADD(t0, zp[2*k],   ntau);   // z - tau (final values)
        PKADD(t1, zp[2*k+1], ntau);
        PKADD(w0, zp[2*k],   nt0);    // z - tau0 (classification)
        PKADD(w1, zp[2*k+1], nt0);
        const float c0 = clipu(w0.x), c1 = clipu(w0.y);
        const float c2 = clipu(w1.x), c3 = clipu(w1.y);
        float4 o;
        o.x = ((c0 > EPS) && (c0 < ucut)) ? t0.x : ((c0 >= ucut) ? MAX_W : 0.0f);
        o.y = ((c1 > EPS) && (c1 < ucut)) ? t0.y : ((c1 >= ucut) ? MAX_W : 0.0f);
        o.z = ((c2 > EPS) && (c2 < ucut)) ? t1.x : ((c2 >= ucut) ? MAX_W : 0.0f);
        o.w = ((c3 > EPS) && (c3 < ucut)) ? t1.y : ((c3 >= ucut) ? MAX_W : 0.0f);
        outr[k * 64 + lane] = o;
    }
}

extern "C" void kernel_launch(void* const* d_in, const int* in_sizes, int n_in,
                              void* d_out, int out_size, void* d_ws, size_t ws_size,
                              hipStream_t stream) {
    const float* x    = (const float*)d_in[0];
    const float* temp = (const float*)d_in[1];
    float* out = (float*)d_out;
    (void)in_sizes; (void)n_in; (void)out_size; (void)d_ws; (void)ws_size;

    dim3 grid(N_SAMPLES / 4);   // 4 rows (waves) per 256-thread block
    dim3 block(256);
    hipLaunchKernelGGL(sparsemax_alloc_kernel, grid, block, 0, stream, x, temp, out);
}